// Round 17
// baseline (699.252 us; speedup 1.0000x reference)
//
#include <hip/hip_runtime.h>
#include <hip/hip_bf16.h>

typedef unsigned short ushortT;
typedef __attribute__((ext_vector_type(8))) short short8;
typedef __attribute__((ext_vector_type(4))) float f32x4;
typedef __attribute__((address_space(3))) unsigned int lds_uint;
typedef __attribute__((address_space(1))) const unsigned int glob_uint;

#define MFMA16(a,b,c) __builtin_amdgcn_mfma_f32_16x16x32_bf16(a,b,c,0,0,0)

__device__ __forceinline__ ushortT f2bf(float f){
  union {float f; unsigned u;} v; v.f = f;
  unsigned r = v.u + 0x7FFFu + ((v.u >> 16) & 1u);
  return (ushortT)(r >> 16);
}
__device__ __forceinline__ float bf2f(ushortT u){
  union {unsigned u; float f;} v; v.u = ((unsigned)u) << 16; return v.f;
}
__device__ __forceinline__ float gelu_f(float v){
  float u = 0.7978845608028654f * (v + 0.044715f*v*v*v);
  float e = __expf(2.0f*u);
  return 0.5f * v * (1.0f + (1.0f - 2.0f/(e + 1.0f)));
}

// B=64, C=192, IMG=56, WS=7, SS=3, NH=6, DH=32, N=49, nWs=8, windows=4096, T=200704
#define SCALE_Q 0.17677669529663687f

// ---------------- k_init: fused {NCHW->NHWC transpose} + {weight prep} ----------------
__global__ void k_init(const float* __restrict__ x,
                       const float* __restrict__ rpb, const float* __restrict__ wqkv,
                       const float* __restrict__ bqkv, const float* __restrict__ wproj,
                       const float* __restrict__ wfc1, const float* __restrict__ wfc2,
                       ushortT* __restrict__ xsb,
                       ushortT* __restrict__ wqkvp, float* __restrict__ bqkvp,
                       ushortT* __restrict__ wprojb, ushortT* __restrict__ wfc1b,
                       ushortT* __restrict__ wfc2b, float* __restrict__ bm)
{
  __shared__ float tile[192*57];
  if (blockIdx.x < 3584){
    int bh = blockIdx.x; int b = bh / 56, h = bh % 56;
    const float* src = x + (size_t)b*602112 + (size_t)h*56;
    for (int e = threadIdx.x; e < 192*56; e += 256){
      int c = e / 56, w = e % 56;
      tile[c*57 + w] = src[(size_t)c*3136 + w];
    }
    __syncthreads();
    ushortT* dst = xsb + (size_t)bh*56*192;
    for (int e = threadIdx.x; e < 56*192; e += 256){
      int w = e / 192, c = e % 192;
      dst[(size_t)w*192 + c] = f2bf(tile[c*57 + w]);
    }
    return;
  }
  int i = (blockIdx.x - 3584) * 256 + threadIdx.x;
  if (i < 110592){ // w_qkv permuted: out row rp = s*192 + h*32 + d  <- in row d*18+h*3+s
    int rp = i / 192, c = i % 192;
    int s = rp / 192, rem = rp % 192, hh = rem / 32, d = rem % 32;
    int rin = d*18 + hh*3 + s;
    float v = wqkv[rin*192 + c];
    if (s == 0) v *= SCALE_Q;
    wqkvp[i] = f2bf(v);
    return;
  }
  i -= 110592;
  if (i < 576){
    int rp = i;
    int s = rp / 192, rem = rp % 192, hh = rem / 32, d = rem % 32;
    int rin = d*18 + hh*3 + s;
    float v = bqkv[rin];
    if (s == 0) v *= SCALE_Q;
    bqkvp[i] = v;
    return;
  }
  i -= 576;
  if (i < 36864){ wprojb[i] = f2bf(wproj[i]); return; }
  i -= 36864;
  if (i < 147456){ wfc1b[i] = f2bf(wfc1[i]); return; }
  i -= 147456;
  if (i < 147456){ wfc2b[i] = f2bf(wfc2[i]); return; }
  i -= 147456;
  if (i < 921984){ // bm[w][h][i][j] = rel-pos-bias + shift-mask
    int j = i % 49; int t = i / 49; int ii = t % 49; t /= 49; int hh = t % 6; int w = t / 6;
    int r1 = ii/7, c1 = ii%7, r2 = j/7, c2 = j%7;
    int idx = (r1 - r2 + 6)*13 + (c1 - c2 + 6);
    float bias = rpb[idx*6 + hh];
    int wy = w >> 3, wx = w & 7;
    int hi = wy*7 + r1, wi = wx*7 + c1, hj = wy*7 + r2, wj = wx*7 + c2;
    int regi = 3*((hi<49)?0:((hi<53)?1:2)) + ((wi<49)?0:((wi<53)?1:2));
    int regj = 3*((hj<49)?0:((hj<53)?1:2)) + ((wj<49)?0:((wj<53)?1:2));
    bm[i] = bias + ((regi != regj) ? -100.0f : 0.0f);
  }
}

// ---------------- k_attn (R16 champion + T1 XCD-aware block swizzle) ----------------
// LDS 52,832B -> 3 blocks/CU; split-head two-pass; persistent a[4][6]; setprio on MFMA.
// Swizzle: 4096 blocks % 8 XCDs == 0 -> wid = (bid&7)*512 + (bid>>3) is bijective;
// each XCD owns 8 contiguous batches -> rolled-window overlap + bm/weights stay L2-local.
__global__ __launch_bounds__(256,3) void k_attn(
  ushortT* __restrict__ xsb, const ushortT* __restrict__ wqkvp, const float* __restrict__ bqkvp,
  const ushortT* __restrict__ wprojb, const float* __restrict__ bproj,
  const float* __restrict__ g0, const float* __restrict__ be0,
  const float* __restrict__ g1, const float* __restrict__ be1,
  const float* __restrict__ bm, ushortT* __restrict__ xs2b)
{
  __shared__ ushortT ln0[49][200];    // LN0 -> Q -> attn-out -> proj-out
  __shared__ ushortT ksh[49][104];    // K for current head-half (96 cols + pad)
  __shared__ ushortT vTh[3][32][72];  // V^T for current head-half
  __shared__ ushortT Pw[4][16][72];   // per-wave softmax probs

  const int tid = threadIdx.x;
  const int lane = tid & 63, wv = tid >> 6;
  const int l15 = lane & 15, g = lane >> 4;
  const int wid0 = blockIdx.x;
  const int wid = (wid0 & 7) * 512 + (wid0 >> 3);   // XCD-aware bijective swizzle
  const int b = wid >> 6, wloc = wid & 63, wy = wloc >> 3, wx = wloc & 7;
  const int mbase = wv * 16;

  // Phase 2: LN0 from global (rolled window rows) -> ln0
  for (int t = wv; t < 49; t += 4){
    int r = t / 7, cc = t % 7;
    int hsrc = (wy*7 + r + 3) % 56;
    int wsrc = (wx*7 + cc + 3) % 56;
    const ushortT* px = xsb + ((size_t)((b*56 + hsrc)*56 + wsrc))*192;
    float x0 = bf2f(px[lane]), x1 = bf2f(px[lane+64]), x2 = bf2f(px[lane+128]);
    float s = x0 + x1 + x2, sq = x0*x0 + x1*x1 + x2*x2;
    #pragma unroll
    for (int m = 1; m < 64; m <<= 1){ s += __shfl_xor(s, m, 64); sq += __shfl_xor(sq, m, 64); }
    float mu = s * (1.0f/192.0f);
    float var = sq * (1.0f/192.0f) - mu*mu;
    float rs = rsqrtf(var + 1e-5f);
    ln0[t][lane]     = f2bf((x0-mu)*rs*g0[lane]     + be0[lane]);
    ln0[t][lane+64]  = f2bf((x1-mu)*rs*g0[lane+64]  + be0[lane+64]);
    ln0[t][lane+128] = f2bf((x2-mu)*rs*g0[lane+128] + be0[lane+128]);
  }
  __syncthreads();

  // Phase 3a: persistent A-fragments (all 64 row-positions) into registers
  short8 a[4][6];
  #pragma unroll
  for (int mt = 0; mt < 4; mt++){
    int ra = mt*16 + l15; if (ra > 48) ra = 48;   // clamp (dup rows masked later)
    #pragma unroll
    for (int kc = 0; kc < 6; kc++)
      a[mt][kc] = *(const short8*)(&ln0[ra][kc*32 + g*8]);
  }
  __syncthreads();   // all LN0 reads done before Q overwrites ln0

  // Phase 3b: half-0 tiles — Q all (nt 0..11), K heads 0-2 (12..17), V heads 0-2 (24..29)
  for (int ntl = 0; ntl < 6; ntl++){
    int idx = wv*6 + ntl;
    int nt = (idx < 18) ? idx : idx + 6;
    int cp = nt*16 + l15;
    const ushortT* wp = wqkvp + (size_t)cp*192 + g*8;
    short8 bfr[6];
    #pragma unroll
    for (int kc = 0; kc < 6; kc++) bfr[kc] = *(const short8*)(wp + kc*32);
    float bias = bqkvp[cp];
    #pragma unroll
    for (int mt = 0; mt < 4; mt++){
      f32x4 acc = {0.f,0.f,0.f,0.f};
      __builtin_amdgcn_s_setprio(1);
      #pragma unroll
      for (int kc = 0; kc < 6; kc++) acc = MFMA16(a[mt][kc], bfr[kc], acc);
      __builtin_amdgcn_s_setprio(0);
      #pragma unroll
      for (int r = 0; r < 4; r++){
        int tok = mt*16 + g*4 + r;
        float v = acc[r] + bias;
        if (cp < 192)      { if (tok < 49) ln0[tok][cp] = f2bf(v); }
        else if (cp < 384) { if (tok < 49) ksh[tok][cp-192] = f2bf(v); }
        else { int c2 = cp - 384; vTh[c2>>5][c2&31][tok] = f2bf(v); }
      }
    }
  }
  __syncthreads();

  // Phase 4 (half 0): heads 0..2 on own 16 q-rows
  const int rq = (mbase + l15 > 48) ? 48 : (mbase + l15);
  for (int hl = 0; hl < 3; hl++){
    int h = hl;                      // global head
    float bmv[4][4];
    #pragma unroll
    for (int r = 0; r < 4; r++){
      int i = mbase + g*4 + r;
      int ic = (i < 49) ? i : 48;
      const float* bmrow = bm + (((size_t)(wloc*6 + h)*49 + ic)*49);
      #pragma unroll
      for (int jt = 0; jt < 4; jt++){
        int j = jt*16 + l15;
        bmv[r][jt] = (i < 49 && j < 49) ? bmrow[j] : -1e30f;
      }
    }
    short8 aq = *(const short8*)(&ln0[rq][h*32 + g*8]);
    f32x4 sreg[4];
    __builtin_amdgcn_s_setprio(1);
    #pragma unroll
    for (int jt = 0; jt < 4; jt++){
      int rk = jt*16 + l15; if (rk > 48) rk = 48;
      short8 bk = *(const short8*)(&ksh[rk][hl*32 + g*8]);
      f32x4 z = {0.f,0.f,0.f,0.f};
      sreg[jt] = MFMA16(aq, bk, z);
    }
    __builtin_amdgcn_s_setprio(0);
    #pragma unroll
    for (int r = 0; r < 4; r++){
      float rv[4];
      #pragma unroll
      for (int jt = 0; jt < 4; jt++){
        float bmvv = bmv[r][jt];
        rv[jt] = (bmvv < -1e29f) ? -1e30f : sreg[jt][r] + bmvv;
      }
      float mx = fmaxf(fmaxf(rv[0],rv[1]), fmaxf(rv[2],rv[3]));
      #pragma unroll
      for (int m = 1; m < 16; m <<= 1) mx = fmaxf(mx, __shfl_xor(mx, m, 64));
      float sum = 0.f;
      #pragma unroll
      for (int jt = 0; jt < 4; jt++){ rv[jt] = __expf(rv[jt] - mx); sum += rv[jt]; }
      #pragma unroll
      for (int m = 1; m < 16; m <<= 1) sum += __shfl_xor(sum, m, 64);
      float rden = 1.0f / sum;
      #pragma unroll
      for (int jt = 0; jt < 4; jt++)
        Pw[wv][g*4+r][jt*16 + l15] = f2bf(rv[jt] * rden);
    }
    #pragma unroll
    for (int nt2 = 0; nt2 < 2; nt2++){
      f32x4 oacc = {0.f,0.f,0.f,0.f};
      __builtin_amdgcn_s_setprio(1);
      #pragma unroll
      for (int kk = 0; kk < 2; kk++){
        short8 ap = *(const short8*)(&Pw[wv][l15][kk*32 + g*8]);
        short8 bv = *(const short8*)(&vTh[hl][nt2*16 + l15][kk*32 + g*8]);
        oacc = MFMA16(ap, bv, oacc);
      }
      __builtin_amdgcn_s_setprio(0);
      #pragma unroll
      for (int r = 0; r < 4; r++){
        int tok = mbase + g*4 + r;
        if (tok < 49) ln0[tok][h*32 + nt2*16 + l15] = f2bf(oacc[r]);
      }
    }
  }
  __syncthreads();   // half-0 K/V dead

  // Phase 3c: half-1 tiles — K heads 3-5 (nt 18..23), V heads 3-5 (30..35); a[] reused
  for (int ntl = 0; ntl < 3; ntl++){
    int idx = wv*3 + ntl;
    int nt = (idx < 6) ? 18 + idx : 24 + idx;
    int cp = nt*16 + l15;
    const ushortT* wp = wqkvp + (size_t)cp*192 + g*8;
    short8 bfr[6];
    #pragma unroll
    for (int kc = 0; kc < 6; kc++) bfr[kc] = *(const short8*)(wp + kc*32);
    float bias = bqkvp[cp];
    #pragma unroll
    for (int mt = 0; mt < 4; mt++){
      f32x4 acc = {0.f,0.f,0.f,0.f};
      __builtin_amdgcn_s_setprio(1);
      #pragma unroll
      for (int kc = 0; kc < 6; kc++) acc = MFMA16(a[mt][kc], bfr[kc], acc);
      __builtin_amdgcn_s_setprio(0);
      #pragma unroll
      for (int r = 0; r < 4; r++){
        int tok = mt*16 + g*4 + r;
        float v = acc[r] + bias;
        if (cp < 384) { if (tok < 49) ksh[tok][cp-288] = f2bf(v); }
        else { int c2 = cp - 480; vTh[c2>>5][c2&31][tok] = f2bf(v); }
      }
    }
  }
  __syncthreads();

  // Phase 4 (half 1): heads 3..5
  for (int hl = 0; hl < 3; hl++){
    int h = 3 + hl;
    float bmv[4][4];
    #pragma unroll
    for (int r = 0; r < 4; r++){
      int i = mbase + g*4 + r;
      int ic = (i < 49) ? i : 48;
      const float* bmrow = bm + (((size_t)(wloc*6 + h)*49 + ic)*49);
      #pragma unroll
      for (int jt = 0; jt < 4; jt++){
        int j = jt*16 + l15;
        bmv[r][jt] = (i < 49 && j < 49) ? bmrow[j] : -1e30f;
      }
    }
    short8 aq = *(const short8*)(&ln0[rq][h*32 + g*8]);
    f32x4 sreg[4];
    __builtin_amdgcn_s_setprio(1);
    #pragma unroll
    for (int jt = 0; jt < 4; jt++){
      int rk = jt*16 + l15; if (rk > 48) rk = 48;
      short8 bk = *(const short8*)(&ksh[rk][hl*32 + g*8]);
      f32x4 z = {0.f,0.f,0.f,0.f};
      sreg[jt] = MFMA16(aq, bk, z);
    }
    __builtin_amdgcn_s_setprio(0);
    #pragma unroll
    for (int r = 0; r < 4; r++){
      float rv[4];
      #pragma unroll
      for (int jt = 0; jt < 4; jt++){
        float bmvv = bmv[r][jt];
        rv[jt] = (bmvv < -1e29f) ? -1e30f : sreg[jt][r] + bmvv;
      }
      float mx = fmaxf(fmaxf(rv[0],rv[1]), fmaxf(rv[2],rv[3]));
      #pragma unroll
      for (int m = 1; m < 16; m <<= 1) mx = fmaxf(mx, __shfl_xor(mx, m, 64));
      float sum = 0.f;
      #pragma unroll
      for (int jt = 0; jt < 4; jt++){ rv[jt] = __expf(rv[jt] - mx); sum += rv[jt]; }
      #pragma unroll
      for (int m = 1; m < 16; m <<= 1) sum += __shfl_xor(sum, m, 64);
      float rden = 1.0f / sum;
      #pragma unroll
      for (int jt = 0; jt < 4; jt++)
        Pw[wv][g*4+r][jt*16 + l15] = f2bf(rv[jt] * rden);
    }
    #pragma unroll
    for (int nt2 = 0; nt2 < 2; nt2++){
      f32x4 oacc = {0.f,0.f,0.f,0.f};
      __builtin_amdgcn_s_setprio(1);
      #pragma unroll
      for (int kk = 0; kk < 2; kk++){
        short8 ap = *(const short8*)(&Pw[wv][l15][kk*32 + g*8]);
        short8 bv = *(const short8*)(&vTh[hl][nt2*16 + l15][kk*32 + g*8]);
        oacc = MFMA16(ap, bv, oacc);
      }
      __builtin_amdgcn_s_setprio(0);
      #pragma unroll
      for (int r = 0; r < 4; r++){
        int tok = mbase + g*4 + r;
        if (tok < 49) ln0[tok][h*32 + nt2*16 + l15] = f2bf(oacc[r]);
      }
    }
  }
  __syncthreads();

  // Phase 5a: proj GEMM — waves split the 12 output-col tiles; proj-out -> ln0
  {
    short8 a2[4][6];
    #pragma unroll
    for (int mt = 0; mt < 4; mt++){
      int ra = mt*16 + l15; if (ra > 48) ra = 48;
      #pragma unroll
      for (int kc = 0; kc < 6; kc++)
        a2[mt][kc] = *(const short8*)(&ln0[ra][kc*32 + g*8]);
    }
    __syncthreads();
    #pragma unroll
    for (int ntl = 0; ntl < 3; ntl++){
      int nt = wv*3 + ntl;
      int cp = nt*16 + l15;
      const ushortT* wp = wprojb + (size_t)cp*192 + g*8;
      short8 bfr[6];
      #pragma unroll
      for (int kc = 0; kc < 6; kc++) bfr[kc] = *(const short8*)(wp + kc*32);
      #pragma unroll
      for (int mt = 0; mt < 4; mt++){
        f32x4 acc = {0.f,0.f,0.f,0.f};
        __builtin_amdgcn_s_setprio(1);
        #pragma unroll
        for (int kc = 0; kc < 6; kc++) acc = MFMA16(a2[mt][kc], bfr[kc], acc);
        __builtin_amdgcn_s_setprio(0);
        #pragma unroll
        for (int r = 0; r < 4; r++){
          int tok = mt*16 + g*4 + r;
          if (tok < 49) ln0[tok][cp] = f2bf(acc[r]);
        }
      }
    }
  }
  __syncthreads();

  // Phase 5b: residual (re-read global) + LN1 + global writes
  for (int t = wv; t < 49; t += 4){
    int rr = t / 7, cc = t % 7;
    int hdst = (wy*7 + rr + 3) % 56, wdst = (wx*7 + cc + 3) % 56;
    size_t gtok = ((size_t)(b*56 + hdst)*56 + wdst)*192;
    float v0 = bf2f(ln0[t][lane])     + bproj[lane]     + bf2f(xsb[gtok + lane]);
    float v1 = bf2f(ln0[t][lane+64])  + bproj[lane+64]  + bf2f(xsb[gtok + lane+64]);
    float v2 = bf2f(ln0[t][lane+128]) + bproj[lane+128] + bf2f(xsb[gtok + lane+128]);
    float s = v0 + v1 + v2, sq = v0*v0 + v1*v1 + v2*v2;
    #pragma unroll
    for (int m = 1; m < 64; m <<= 1){ s += __shfl_xor(s, m, 64); sq += __shfl_xor(sq, m, 64); }
    float mu = s * (1.0f/192.0f);
    float var = sq * (1.0f/192.0f) - mu*mu;
    float rs = rsqrtf(var + 1e-5f);
    xs2b[gtok + lane]     = f2bf(v0);
    xs2b[gtok + lane+64]  = f2bf(v1);
    xs2b[gtok + lane+128] = f2bf(v2);
    xsb[gtok + lane]     = f2bf((v0-mu)*rs*g1[lane]     + be1[lane]);
    xsb[gtok + lane+64]  = f2bf((v1-mu)*rs*g1[lane+64]  + be1[lane+64]);
    xsb[gtok + lane+128] = f2bf((v2-mu)*rs*g1[lane+128] + be1[lane+128]);
  }
}

// ---------------- k_mlp_fused v5: global_load_lds dbuf weight pipeline (R9, best) --------
__global__ __launch_bounds__(512,4) void k_mlp_fused(
  const ushortT* __restrict__ A,      // LN1 out, bf16 [200704][192]
  const ushortT* __restrict__ w1g,    // bf16 [768][192]
  const float* __restrict__ b1,
  const ushortT* __restrict__ w2g,    // bf16 [192][768]
  const float* __restrict__ b2,
  const ushortT* __restrict__ xs2b,   // residual bf16 [200704][192]
  float* __restrict__ out)            // NCHW f32
{
  __shared__ ushortT w1s[2][6144];    // 2 x 12,288 B  (768 16B-units, fragment order)
  __shared__ ushortT w2s[2][6144];    // 2 x 12,288 B
  __shared__ ushortT Hbuf[128][40];   // 10,240 B (wave-private 16-row slices, K=32)
  // total 59,392 B -> 2 blocks/CU

  const int tid = threadIdx.x, lane = tid & 63, wv = tid >> 6;
  const int l15 = lane & 15, g = lane >> 4;
  const size_t Mbase = (size_t)blockIdx.x * 128;
  const int rowb = wv * 16;

  // A fragments (read-once stream)
  short8 a[6];
  {
    size_t row = Mbase + rowb + l15;
    #pragma unroll
    for (int kc = 0; kc < 6; kc++)
      a[kc] = __builtin_nontemporal_load((const short8*)(A + row*192 + kc*32 + g*8));
  }

  // async stage of slice HB into buffer NB: 24 x 1KB chunks, 3 per wave
  #define STAGE(HB, NB)                                                         \
    _Pragma("unroll")                                                           \
    for (int j = 0; j < 3; j++){                                                \
      int id = wv + j*8;                                                        \
      if (id < 12){                                                             \
        int ci = id;                                                            \
        int q = ci*4 + (lane >> 4);                                             \
        int gq = q & 3, t = q >> 2;                                             \
        int nt = t / 6, kc = t % 6;                                             \
        const ushortT* src = w1g + (size_t)((HB)*32 + nt*16 + (lane & 15))*192  \
                             + kc*32 + gq*8;                                    \
        __builtin_amdgcn_global_load_lds((glob_uint*)src,                       \
            (lds_uint*)(&w1s[NB][ci*512]), 16, 0, 0);                           \
      } else {                                                                  \
        int ci = id - 12;                                                       \
        int q = ci*4 + (lane >> 4);                                             \
        int nt = q >> 2, gq = q & 3;                                            \
        const ushortT* src = w2g + (size_t)(nt*16 + (lane & 15))*768            \
                             + (HB)*32 + gq*8;                                  \
        __builtin_amdgcn_global_load_lds((glob_uint*)src,                       \
            (lds_uint*)(&w2s[NB][ci*512]), 16, 0, 0);                           \
      }                                                                         \
    }

  STAGE(0, 0);
  __syncthreads();                    // drains vmcnt: slice 0 resident

  f32x4 acc2[12];
  #pragma unroll
  for (int nt = 0; nt < 12; nt++) acc2[nt] = (f32x4){0.f,0.f,0.f,0.f};

  for (int hb = 0; hb < 24; hb++){
    const int cb = hb & 1;
    if (hb < 23){ STAGE(hb+1, cb^1); }   // async; lands during compute below

    // fc1 + GELU -> Hbuf (own 16 rows); weights from fragment-LDS
    #pragma unroll
    for (int nt = 0; nt < 2; nt++){
      short8 bfr[6];
      #pragma unroll
      for (int kc = 0; kc < 6; kc++){
        int q = (nt*6 + kc)*4 + g;
        bfr[kc] = *(const short8*)(&w1s[cb][(q*16 + l15)*8]);
      }
      float bias = b1[hb*32 + nt*16 + l15];
      f32x4 acc = {0.f,0.f,0.f,0.f};
      #pragma unroll
      for (int kc = 0; kc < 6; kc++) acc = MFMA16(a[kc], bfr[kc], acc);
      #pragma unroll
      for (int r = 0; r < 4; r++)
        Hbuf[rowb + g*4 + r][nt*16 + l15] = f2bf(gelu_f(acc[r] + bias));
    }
    // fc2 partial (K=32): H from own rows (wave-local)
    short8 h2f = *(const short8*)(&Hbuf[rowb + l15][g*8]);
    #pragma unroll
    for (int nt = 0; nt < 12; nt++){
      int q2 = nt*4 + g;
      short8 wfr = *(const short8*)(&w2s[cb][(q2*16 + l15)*8]);
      acc2[nt] = MFMA16(h2f, wfr, acc2[nt]);
    }
    __syncthreads();   // implicit vmcnt(0): next slice resident; buf[cb] free
  }

  // Epilogue: + b2 + residual -> NCHW f32
  #pragma unroll
  for (int nt = 0; nt < 12; nt++){
    int c = nt*16 + l15;
    float bs = b2[c];
    #pragma unroll
    for (int r = 0; r < 4; r++){
      size_t tok = Mbase + rowb + g*4 + r;
      float v = acc2[nt][r] + bs + bf2f(xs2b[tok*192 + c]);
      unsigned t32 = (unsigned)tok;
      unsigned bb = t32 / 3136u, rem = t32 % 3136u;
      out[(size_t)bb*602112 + (size_t)c*3136 + rem] = v;
    }
  }
  #undef STAGE
}

// ---------------- launch ----------------
extern "C" void kernel_launch(void* const* d_in, const int* in_sizes, int n_in,
                              void* d_out, int out_size, void* d_ws, size_t ws_size,
                              hipStream_t stream)
{
  const float* x      = (const float*)d_in[0];
  const float* rpb    = (const float*)d_in[1];
  const float* w_qkv  = (const float*)d_in[2];
  const float* b_qkv  = (const float*)d_in[3];
  const float* w_proj = (const float*)d_in[4];
  const float* b_proj = (const float*)d_in[5];
  const float* g0     = (const float*)d_in[6];
  const float* be0    = (const float*)d_in[7];
  const float* g1     = (const float*)d_in[8];
  const float* be1    = (const float*)d_in[9];
  const float* w_fc1  = (const float*)d_in[10];
  const float* b_fc1  = (const float*)d_in[11];
  const float* w_fc2  = (const float*)d_in[12];
  const float* b_fc2  = (const float*)d_in[13];
  float* out = (float*)d_out;
  char* ws = (char*)d_ws;

  // Workspace layout (ends at 158,715,648 B ~= 159 MB)
  ushortT* xsb    = (ushortT*)(ws);                    // 77,070,336 B raw NHWC bf16 -> LN1-out
  ushortT* xs2b   = (ushortT*)(ws + 77070336);         // 77,070,336 B residual bf16
  ushortT* wqkvp  = (ushortT*)(ws + 154140672);        // 221,184 B
  float*   bqkvp  = (float*)(ws + 154361856);          // 2,304 B
  ushortT* wprojb = (ushortT*)(ws + 154364160);        // 73,728 B
  ushortT* wfc1b  = (ushortT*)(ws + 154437888);        // 294,912 B
  ushortT* wfc2b  = (ushortT*)(ws + 154732800);        // 294,912 B
  float*   bm     = (float*)(ws + 155027712);          // 3,687,936 B (f32)

  k_init<<<8916, 256, 0, stream>>>(x, rpb, w_qkv, b_qkv, w_proj, w_fc1, w_fc2,
                                   xsb, wqkvp, bqkvp, wprojb, wfc1b, wfc2b, bm);
  k_attn<<<4096, 256, 0, stream>>>(xsb, wqkvp, bqkvp, wprojb, b_proj,
                                   g0, be0, g1, be1, bm, xs2b);
  k_mlp_fused<<<1568, 512, 0, stream>>>(xsb, wfc1b, b_fc1, wfc2b, b_fc2, xs2b, out);
}

// Round 18
// 682.974 us; speedup vs baseline: 1.0238x; 1.0238x over previous
//
#include <hip/hip_runtime.h>
#include <hip/hip_bf16.h>

typedef unsigned short ushortT;
typedef __attribute__((ext_vector_type(8))) short short8;
typedef __attribute__((ext_vector_type(4))) float f32x4;
typedef __attribute__((address_space(3))) unsigned int lds_uint;
typedef __attribute__((address_space(1))) const unsigned int glob_uint;

#define MFMA16(a,b,c) __builtin_amdgcn_mfma_f32_16x16x32_bf16(a,b,c,0,0,0)

__device__ __forceinline__ ushortT f2bf(float f){
  union {float f; unsigned u;} v; v.f = f;
  unsigned r = v.u + 0x7FFFu + ((v.u >> 16) & 1u);
  return (ushortT)(r >> 16);
}
__device__ __forceinline__ float bf2f(ushortT u){
  union {unsigned u; float f;} v; v.u = ((unsigned)u) << 16; return v.f;
}
__device__ __forceinline__ float gelu_f(float v){
  float u = 0.7978845608028654f * (v + 0.044715f*v*v*v);
  float e = __expf(2.0f*u);
  return 0.5f * v * (1.0f + (1.0f - 2.0f/(e + 1.0f)));
}

// B=64, C=192, IMG=56, WS=7, SS=3, NH=6, DH=32, N=49, nWs=8, windows=4096, T=200704
#define SCALE_Q 0.17677669529663687f

// ---------------- k_init: fused {NCHW->NHWC transpose} + {weight prep} ----------------
__global__ void k_init(const float* __restrict__ x,
                       const float* __restrict__ rpb, const float* __restrict__ wqkv,
                       const float* __restrict__ bqkv, const float* __restrict__ wproj,
                       const float* __restrict__ wfc1, const float* __restrict__ wfc2,
                       ushortT* __restrict__ xsb,
                       ushortT* __restrict__ wqkvp, float* __restrict__ bqkvp,
                       ushortT* __restrict__ wprojb, ushortT* __restrict__ wfc1b,
                       ushortT* __restrict__ wfc2b, float* __restrict__ bm)
{
  __shared__ float tile[192*57];
  if (blockIdx.x < 3584){
    int bh = blockIdx.x; int b = bh / 56, h = bh % 56;
    const float* src = x + (size_t)b*602112 + (size_t)h*56;
    for (int e = threadIdx.x; e < 192*56; e += 256){
      int c = e / 56, w = e % 56;
      tile[c*57 + w] = src[(size_t)c*3136 + w];
    }
    __syncthreads();
    ushortT* dst = xsb + (size_t)bh*56*192;
    for (int e = threadIdx.x; e < 56*192; e += 256){
      int w = e / 192, c = e % 192;
      dst[(size_t)w*192 + c] = f2bf(tile[c*57 + w]);
    }
    return;
  }
  int i = (blockIdx.x - 3584) * 256 + threadIdx.x;
  if (i < 110592){ // w_qkv permuted: out row rp = s*192 + h*32 + d  <- in row d*18+h*3+s
    int rp = i / 192, c = i % 192;
    int s = rp / 192, rem = rp % 192, hh = rem / 32, d = rem % 32;
    int rin = d*18 + hh*3 + s;
    float v = wqkv[rin*192 + c];
    if (s == 0) v *= SCALE_Q;
    wqkvp[i] = f2bf(v);
    return;
  }
  i -= 110592;
  if (i < 576){
    int rp = i;
    int s = rp / 192, rem = rp % 192, hh = rem / 32, d = rem % 32;
    int rin = d*18 + hh*3 + s;
    float v = bqkv[rin];
    if (s == 0) v *= SCALE_Q;
    bqkvp[i] = v;
    return;
  }
  i -= 576;
  if (i < 36864){ wprojb[i] = f2bf(wproj[i]); return; }
  i -= 36864;
  if (i < 147456){ wfc1b[i] = f2bf(wfc1[i]); return; }
  i -= 147456;
  if (i < 147456){ wfc2b[i] = f2bf(wfc2[i]); return; }
  i -= 147456;
  if (i < 921984){ // bm[w][h][i][j] = rel-pos-bias + shift-mask
    int j = i % 49; int t = i / 49; int ii = t % 49; t /= 49; int hh = t % 6; int w = t / 6;
    int r1 = ii/7, c1 = ii%7, r2 = j/7, c2 = j%7;
    int idx = (r1 - r2 + 6)*13 + (c1 - c2 + 6);
    float bias = rpb[idx*6 + hh];
    int wy = w >> 3, wx = w & 7;
    int hi = wy*7 + r1, wi = wx*7 + c1, hj = wy*7 + r2, wj = wx*7 + c2;
    int regi = 3*((hi<49)?0:((hi<53)?1:2)) + ((wi<49)?0:((wi<53)?1:2));
    int regj = 3*((hj<49)?0:((hj<53)?1:2)) + ((wj<49)?0:((wj<53)?1:2));
    bm[i] = bias + ((regi != regj) ? -100.0f : 0.0f);
  }
}

// ---------------- k_attn (champion): split-head two-pass, 3 blocks/CU, setprio ----------------
__global__ __launch_bounds__(256,3) void k_attn(
  ushortT* __restrict__ xsb, const ushortT* __restrict__ wqkvp, const float* __restrict__ bqkvp,
  const ushortT* __restrict__ wprojb, const float* __restrict__ bproj,
  const float* __restrict__ g0, const float* __restrict__ be0,
  const float* __restrict__ g1, const float* __restrict__ be1,
  const float* __restrict__ bm, ushortT* __restrict__ xs2b)
{
  __shared__ ushortT ln0[49][200];    // LN0 -> Q -> attn-out -> proj-out
  __shared__ ushortT ksh[49][104];    // K for current head-half (96 cols + pad)
  __shared__ ushortT vTh[3][32][72];  // V^T for current head-half
  __shared__ ushortT Pw[4][16][72];   // per-wave softmax probs

  const int tid = threadIdx.x;
  const int lane = tid & 63, wv = tid >> 6;
  const int l15 = lane & 15, g = lane >> 4;
  const int wid = blockIdx.x;
  const int b = wid >> 6, wloc = wid & 63, wy = wloc >> 3, wx = wloc & 7;
  const int mbase = wv * 16;

  // Phase 2: LN0 from global (rolled window rows) -> ln0
  for (int t = wv; t < 49; t += 4){
    int r = t / 7, cc = t % 7;
    int hsrc = (wy*7 + r + 3) % 56;
    int wsrc = (wx*7 + cc + 3) % 56;
    const ushortT* px = xsb + ((size_t)((b*56 + hsrc)*56 + wsrc))*192;
    float x0 = bf2f(px[lane]), x1 = bf2f(px[lane+64]), x2 = bf2f(px[lane+128]);
    float s = x0 + x1 + x2, sq = x0*x0 + x1*x1 + x2*x2;
    #pragma unroll
    for (int m = 1; m < 64; m <<= 1){ s += __shfl_xor(s, m, 64); sq += __shfl_xor(sq, m, 64); }
    float mu = s * (1.0f/192.0f);
    float var = sq * (1.0f/192.0f) - mu*mu;
    float rs = rsqrtf(var + 1e-5f);
    ln0[t][lane]     = f2bf((x0-mu)*rs*g0[lane]     + be0[lane]);
    ln0[t][lane+64]  = f2bf((x1-mu)*rs*g0[lane+64]  + be0[lane+64]);
    ln0[t][lane+128] = f2bf((x2-mu)*rs*g0[lane+128] + be0[lane+128]);
  }
  __syncthreads();

  // Phase 3a: persistent A-fragments (all 64 row-positions) into registers
  short8 a[4][6];
  #pragma unroll
  for (int mt = 0; mt < 4; mt++){
    int ra = mt*16 + l15; if (ra > 48) ra = 48;   // clamp (dup rows masked later)
    #pragma unroll
    for (int kc = 0; kc < 6; kc++)
      a[mt][kc] = *(const short8*)(&ln0[ra][kc*32 + g*8]);
  }
  __syncthreads();   // all LN0 reads done before Q overwrites ln0

  // Phase 3b: half-0 tiles — Q all (nt 0..11), K heads 0-2 (12..17), V heads 0-2 (24..29)
  for (int ntl = 0; ntl < 6; ntl++){
    int idx = wv*6 + ntl;
    int nt = (idx < 18) ? idx : idx + 6;
    int cp = nt*16 + l15;
    const ushortT* wp = wqkvp + (size_t)cp*192 + g*8;
    short8 bfr[6];
    #pragma unroll
    for (int kc = 0; kc < 6; kc++) bfr[kc] = *(const short8*)(wp + kc*32);
    float bias = bqkvp[cp];
    #pragma unroll
    for (int mt = 0; mt < 4; mt++){
      f32x4 acc = {0.f,0.f,0.f,0.f};
      __builtin_amdgcn_s_setprio(1);
      #pragma unroll
      for (int kc = 0; kc < 6; kc++) acc = MFMA16(a[mt][kc], bfr[kc], acc);
      __builtin_amdgcn_s_setprio(0);
      #pragma unroll
      for (int r = 0; r < 4; r++){
        int tok = mt*16 + g*4 + r;
        float v = acc[r] + bias;
        if (cp < 192)      { if (tok < 49) ln0[tok][cp] = f2bf(v); }
        else if (cp < 384) { if (tok < 49) ksh[tok][cp-192] = f2bf(v); }
        else { int c2 = cp - 384; vTh[c2>>5][c2&31][tok] = f2bf(v); }
      }
    }
  }
  __syncthreads();

  // Phase 4 (half 0): heads 0..2 on own 16 q-rows
  const int rq = (mbase + l15 > 48) ? 48 : (mbase + l15);
  for (int hl = 0; hl < 3; hl++){
    int h = hl;                      // global head
    float bmv[4][4];
    #pragma unroll
    for (int r = 0; r < 4; r++){
      int i = mbase + g*4 + r;
      int ic = (i < 49) ? i : 48;
      const float* bmrow = bm + (((size_t)(wloc*6 + h)*49 + ic)*49);
      #pragma unroll
      for (int jt = 0; jt < 4; jt++){
        int j = jt*16 + l15;
        bmv[r][jt] = (i < 49 && j < 49) ? bmrow[j] : -1e30f;
      }
    }
    short8 aq = *(const short8*)(&ln0[rq][h*32 + g*8]);
    f32x4 sreg[4];
    __builtin_amdgcn_s_setprio(1);
    #pragma unroll
    for (int jt = 0; jt < 4; jt++){
      int rk = jt*16 + l15; if (rk > 48) rk = 48;
      short8 bk = *(const short8*)(&ksh[rk][hl*32 + g*8]);
      f32x4 z = {0.f,0.f,0.f,0.f};
      sreg[jt] = MFMA16(aq, bk, z);
    }
    __builtin_amdgcn_s_setprio(0);
    #pragma unroll
    for (int r = 0; r < 4; r++){
      float rv[4];
      #pragma unroll
      for (int jt = 0; jt < 4; jt++){
        float bmvv = bmv[r][jt];
        rv[jt] = (bmvv < -1e29f) ? -1e30f : sreg[jt][r] + bmvv;
      }
      float mx = fmaxf(fmaxf(rv[0],rv[1]), fmaxf(rv[2],rv[3]));
      #pragma unroll
      for (int m = 1; m < 16; m <<= 1) mx = fmaxf(mx, __shfl_xor(mx, m, 64));
      float sum = 0.f;
      #pragma unroll
      for (int jt = 0; jt < 4; jt++){ rv[jt] = __expf(rv[jt] - mx); sum += rv[jt]; }
      #pragma unroll
      for (int m = 1; m < 16; m <<= 1) sum += __shfl_xor(sum, m, 64);
      float rden = 1.0f / sum;
      #pragma unroll
      for (int jt = 0; jt < 4; jt++)
        Pw[wv][g*4+r][jt*16 + l15] = f2bf(rv[jt] * rden);
    }
    #pragma unroll
    for (int nt2 = 0; nt2 < 2; nt2++){
      f32x4 oacc = {0.f,0.f,0.f,0.f};
      __builtin_amdgcn_s_setprio(1);
      #pragma unroll
      for (int kk = 0; kk < 2; kk++){
        short8 ap = *(const short8*)(&Pw[wv][l15][kk*32 + g*8]);
        short8 bv = *(const short8*)(&vTh[hl][nt2*16 + l15][kk*32 + g*8]);
        oacc = MFMA16(ap, bv, oacc);
      }
      __builtin_amdgcn_s_setprio(0);
      #pragma unroll
      for (int r = 0; r < 4; r++){
        int tok = mbase + g*4 + r;
        if (tok < 49) ln0[tok][h*32 + nt2*16 + l15] = f2bf(oacc[r]);
      }
    }
  }
  __syncthreads();   // half-0 K/V dead

  // Phase 3c: half-1 tiles — K heads 3-5 (nt 18..23), V heads 3-5 (30..35); a[] reused
  for (int ntl = 0; ntl < 3; ntl++){
    int idx = wv*3 + ntl;
    int nt = (idx < 6) ? 18 + idx : 24 + idx;
    int cp = nt*16 + l15;
    const ushortT* wp = wqkvp + (size_t)cp*192 + g*8;
    short8 bfr[6];
    #pragma unroll
    for (int kc = 0; kc < 6; kc++) bfr[kc] = *(const short8*)(wp + kc*32);
    float bias = bqkvp[cp];
    #pragma unroll
    for (int mt = 0; mt < 4; mt++){
      f32x4 acc = {0.f,0.f,0.f,0.f};
      __builtin_amdgcn_s_setprio(1);
      #pragma unroll
      for (int kc = 0; kc < 6; kc++) acc = MFMA16(a[mt][kc], bfr[kc], acc);
      __builtin_amdgcn_s_setprio(0);
      #pragma unroll
      for (int r = 0; r < 4; r++){
        int tok = mt*16 + g*4 + r;
        float v = acc[r] + bias;
        if (cp < 384) { if (tok < 49) ksh[tok][cp-288] = f2bf(v); }
        else { int c2 = cp - 480; vTh[c2>>5][c2&31][tok] = f2bf(v); }
      }
    }
  }
  __syncthreads();

  // Phase 4 (half 1): heads 3..5
  for (int hl = 0; hl < 3; hl++){
    int h = 3 + hl;
    float bmv[4][4];
    #pragma unroll
    for (int r = 0; r < 4; r++){
      int i = mbase + g*4 + r;
      int ic = (i < 49) ? i : 48;
      const float* bmrow = bm + (((size_t)(wloc*6 + h)*49 + ic)*49);
      #pragma unroll
      for (int jt = 0; jt < 4; jt++){
        int j = jt*16 + l15;
        bmv[r][jt] = (i < 49 && j < 49) ? bmrow[j] : -1e30f;
      }
    }
    short8 aq = *(const short8*)(&ln0[rq][h*32 + g*8]);
    f32x4 sreg[4];
    __builtin_amdgcn_s_setprio(1);
    #pragma unroll
    for (int jt = 0; jt < 4; jt++){
      int rk = jt*16 + l15; if (rk > 48) rk = 48;
      short8 bk = *(const short8*)(&ksh[rk][hl*32 + g*8]);
      f32x4 z = {0.f,0.f,0.f,0.f};
      sreg[jt] = MFMA16(aq, bk, z);
    }
    __builtin_amdgcn_s_setprio(0);
    #pragma unroll
    for (int r = 0; r < 4; r++){
      float rv[4];
      #pragma unroll
      for (int jt = 0; jt < 4; jt++){
        float bmvv = bmv[r][jt];
        rv[jt] = (bmvv < -1e29f) ? -1e30f : sreg[jt][r] + bmvv;
      }
      float mx = fmaxf(fmaxf(rv[0],rv[1]), fmaxf(rv[2],rv[3]));
      #pragma unroll
      for (int m = 1; m < 16; m <<= 1) mx = fmaxf(mx, __shfl_xor(mx, m, 64));
      float sum = 0.f;
      #pragma unroll
      for (int jt = 0; jt < 4; jt++){ rv[jt] = __expf(rv[jt] - mx); sum += rv[jt]; }
      #pragma unroll
      for (int m = 1; m < 16; m <<= 1) sum += __shfl_xor(sum, m, 64);
      float rden = 1.0f / sum;
      #pragma unroll
      for (int jt = 0; jt < 4; jt++)
        Pw[wv][g*4+r][jt*16 + l15] = f2bf(rv[jt] * rden);
    }
    #pragma unroll
    for (int nt2 = 0; nt2 < 2; nt2++){
      f32x4 oacc = {0.f,0.f,0.f,0.f};
      __builtin_amdgcn_s_setprio(1);
      #pragma unroll
      for (int kk = 0; kk < 2; kk++){
        short8 ap = *(const short8*)(&Pw[wv][l15][kk*32 + g*8]);
        short8 bv = *(const short8*)(&vTh[hl][nt2*16 + l15][kk*32 + g*8]);
        oacc = MFMA16(ap, bv, oacc);
      }
      __builtin_amdgcn_s_setprio(0);
      #pragma unroll
      for (int r = 0; r < 4; r++){
        int tok = mbase + g*4 + r;
        if (tok < 49) ln0[tok][h*32 + nt2*16 + l15] = f2bf(oacc[r]);
      }
    }
  }
  __syncthreads();

  // Phase 5a: proj GEMM — waves split the 12 output-col tiles; proj-out -> ln0
  {
    short8 a2[4][6];
    #pragma unroll
    for (int mt = 0; mt < 4; mt++){
      int ra = mt*16 + l15; if (ra > 48) ra = 48;
      #pragma unroll
      for (int kc = 0; kc < 6; kc++)
        a2[mt][kc] = *(const short8*)(&ln0[ra][kc*32 + g*8]);
    }
    __syncthreads();
    #pragma unroll
    for (int ntl = 0; ntl < 3; ntl++){
      int nt = wv*3 + ntl;
      int cp = nt*16 + l15;
      const ushortT* wp = wprojb + (size_t)cp*192 + g*8;
      short8 bfr[6];
      #pragma unroll
      for (int kc = 0; kc < 6; kc++) bfr[kc] = *(const short8*)(wp + kc*32);
      #pragma unroll
      for (int mt = 0; mt < 4; mt++){
        f32x4 acc = {0.f,0.f,0.f,0.f};
        __builtin_amdgcn_s_setprio(1);
        #pragma unroll
        for (int kc = 0; kc < 6; kc++) acc = MFMA16(a2[mt][kc], bfr[kc], acc);
        __builtin_amdgcn_s_setprio(0);
        #pragma unroll
        for (int r = 0; r < 4; r++){
          int tok = mt*16 + g*4 + r;
          if (tok < 49) ln0[tok][cp] = f2bf(acc[r]);
        }
      }
    }
  }
  __syncthreads();

  // Phase 5b: residual (re-read global) + LN1 + global writes
  for (int t = wv; t < 49; t += 4){
    int rr = t / 7, cc = t % 7;
    int hdst = (wy*7 + rr + 3) % 56, wdst = (wx*7 + cc + 3) % 56;
    size_t gtok = ((size_t)(b*56 + hdst)*56 + wdst)*192;
    float v0 = bf2f(ln0[t][lane])     + bproj[lane]     + bf2f(xsb[gtok + lane]);
    float v1 = bf2f(ln0[t][lane+64])  + bproj[lane+64]  + bf2f(xsb[gtok + lane+64]);
    float v2 = bf2f(ln0[t][lane+128]) + bproj[lane+128] + bf2f(xsb[gtok + lane+128]);
    float s = v0 + v1 + v2, sq = v0*v0 + v1*v1 + v2*v2;
    #pragma unroll
    for (int m = 1; m < 64; m <<= 1){ s += __shfl_xor(s, m, 64); sq += __shfl_xor(sq, m, 64); }
    float mu = s * (1.0f/192.0f);
    float var = sq * (1.0f/192.0f) - mu*mu;
    float rs = rsqrtf(var + 1e-5f);
    xs2b[gtok + lane]     = f2bf(v0);
    xs2b[gtok + lane+64]  = f2bf(v1);
    xs2b[gtok + lane+128] = f2bf(v2);
    xsb[gtok + lane]     = f2bf((v0-mu)*rs*g1[lane]     + be1[lane]);
    xsb[gtok + lane+64]  = f2bf((v1-mu)*rs*g1[lane+64]  + be1[lane+64]);
    xsb[gtok + lane+128] = f2bf((v2-mu)*rs*g1[lane+128] + be1[lane+128]);
  }
}

// ---------------- k_mlp_fused v5: global_load_lds dbuf weight pipeline ----------------
__global__ __launch_bounds__(512,4) void k_mlp_fused(
  const ushortT* __restrict__ A,      // LN1 out, bf16 [200704][192]
  const ushortT* __restrict__ w1g,    // bf16 [768][192]
  const float* __restrict__ b1,
  const ushortT* __restrict__ w2g,    // bf16 [192][768]
  const float* __restrict__ b2,
  const ushortT* __restrict__ xs2b,   // residual bf16 [200704][192]
  float* __restrict__ out)            // NCHW f32
{
  __shared__ ushortT w1s[2][6144];    // 2 x 12,288 B  (768 16B-units, fragment order)
  __shared__ ushortT w2s[2][6144];    // 2 x 12,288 B
  __shared__ ushortT Hbuf[128][40];   // 10,240 B (wave-private 16-row slices, K=32)
  // total 59,392 B -> 2 blocks/CU

  const int tid = threadIdx.x, lane = tid & 63, wv = tid >> 6;
  const int l15 = lane & 15, g = lane >> 4;
  const size_t Mbase = (size_t)blockIdx.x * 128;
  const int rowb = wv * 16;

  // A fragments (read-once stream)
  short8 a[6];
  {
    size_t row = Mbase + rowb + l15;
    #pragma unroll
    for (int kc = 0; kc < 6; kc++)
      a[kc] = __builtin_nontemporal_load((const short8*)(A + row*192 + kc*32 + g*8));
  }

  // async stage of slice HB into buffer NB: 24 x 1KB chunks, 3 per wave
  #define STAGE(HB, NB)                                                         \
    _Pragma("unroll")                                                           \
    for (int j = 0; j < 3; j++){                                                \
      int id = wv + j*8;                                                        \
      if (id < 12){                                                             \
        int ci = id;                                                            \
        int q = ci*4 + (lane >> 4);                                             \
        int gq = q & 3, t = q >> 2;                                             \
        int nt = t / 6, kc = t % 6;                                             \
        const ushortT* src = w1g + (size_t)((HB)*32 + nt*16 + (lane & 15))*192  \
                             + kc*32 + gq*8;                                    \
        __builtin_amdgcn_global_load_lds((glob_uint*)src,                       \
            (lds_uint*)(&w1s[NB][ci*512]), 16, 0, 0);                           \
      } else {                                                                  \
        int ci = id - 12;                                                       \
        int q = ci*4 + (lane >> 4);                                             \
        int nt = q >> 2, gq = q & 3;                                            \
        const ushortT* src = w2g + (size_t)(nt*16 + (lane & 15))*768            \
                             + (HB)*32 + gq*8;                                  \
        __builtin_amdgcn_global_load_lds((glob_uint*)src,                       \
            (lds_uint*)(&w2s[NB][ci*512]), 16, 0, 0);                           \
      }                                                                         \
    }

  STAGE(0, 0);
  __syncthreads();                    // drains vmcnt: slice 0 resident

  f32x4 acc2[12];
  #pragma unroll
  for (int nt = 0; nt < 12; nt++) acc2[nt] = (f32x4){0.f,0.f,0.f,0.f};

  for (int hb = 0; hb < 24; hb++){
    const int cb = hb & 1;
    if (hb < 23){ STAGE(hb+1, cb^1); }   // async; lands during compute below

    // fc1 + GELU -> Hbuf (own 16 rows); weights from fragment-LDS
    #pragma unroll
    for (int nt = 0; nt < 2; nt++){
      short8 bfr[6];
      #pragma unroll
      for (int kc = 0; kc < 6; kc++){
        int q = (nt*6 + kc)*4 + g;
        bfr[kc] = *(const short8*)(&w1s[cb][(q*16 + l15)*8]);
      }
      float bias = b1[hb*32 + nt*16 + l15];
      f32x4 acc = {0.f,0.f,0.f,0.f};
      #pragma unroll
      for (int kc = 0; kc < 6; kc++) acc = MFMA16(a[kc], bfr[kc], acc);
      #pragma unroll
      for (int r = 0; r < 4; r++)
        Hbuf[rowb + g*4 + r][nt*16 + l15] = f2bf(gelu_f(acc[r] + bias));
    }
    // fc2 partial (K=32): H from own rows (wave-local)
    short8 h2f = *(const short8*)(&Hbuf[rowb + l15][g*8]);
    #pragma unroll
    for (int nt = 0; nt < 12; nt++){
      int q2 = nt*4 + g;
      short8 wfr = *(const short8*)(&w2s[cb][(q2*16 + l15)*8]);
      acc2[nt] = MFMA16(h2f, wfr, acc2[nt]);
    }
    __syncthreads();   // implicit vmcnt(0): next slice resident; buf[cb] free
  }

  // Epilogue: + b2 + residual -> NCHW f32
  #pragma unroll
  for (int nt = 0; nt < 12; nt++){
    int c = nt*16 + l15;
    float bs = b2[c];
    #pragma unroll
    for (int r = 0; r < 4; r++){
      size_t tok = Mbase + rowb + g*4 + r;
      float v = acc2[nt][r] + bs + bf2f(xs2b[tok*192 + c]);
      unsigned t32 = (unsigned)tok;
      unsigned bb = t32 / 3136u, rem = t32 % 3136u;
      out[(size_t)bb*602112 + (size_t)c*3136 + rem] = v;
    }
  }
  #undef STAGE
}

// ---------------- launch ----------------
extern "C" void kernel_launch(void* const* d_in, const int* in_sizes, int n_in,
                              void* d_out, int out_size, void* d_ws, size_t ws_size,
                              hipStream_t stream)
{
  const float* x      = (const float*)d_in[0];
  const float* rpb    = (const float*)d_in[1];
  const float* w_qkv  = (const float*)d_in[2];
  const float* b_qkv  = (const float*)d_in[3];
  const float* w_proj = (const float*)d_in[4];
  const float* b_proj = (const float*)d_in[5];
  const float* g0     = (const float*)d_in[6];
  const float* be0    = (const float*)d_in[7];
  const float* g1     = (const float*)d_in[8];
  const float* be1    = (const float*)d_in[9];
  const float* w_fc1  = (const float*)d_in[10];
  const float* b_fc1  = (const float*)d_in[11];
  const float* w_fc2  = (const float*)d_in[12];
  const float* b_fc2  = (const float*)d_in[13];
  float* out = (float*)d_out;
  char* ws = (char*)d_ws;

  // Workspace layout (ends at 158,715,648 B ~= 159 MB)
  ushortT* xsb    = (ushortT*)(ws);                    // 77,070,336 B raw NHWC bf16 -> LN1-out
  ushortT* xs2b   = (ushortT*)(ws + 77070336);         // 77,070,336 B residual bf16
  ushortT* wqkvp  = (ushortT*)(ws + 154140672);        // 221,184 B
  float*   bqkvp  = (float*)(ws + 154361856);          // 2,304 B
  ushortT* wprojb = (ushortT*)(ws + 154364160);        // 73,728 B
  ushortT* wfc1b  = (ushortT*)(ws + 154437888);        // 294,912 B
  ushortT* wfc2b  = (ushortT*)(ws + 154732800);        // 294,912 B
  float*   bm     = (float*)(ws + 155027712);          // 3,687,936 B (f32)

  k_init<<<8916, 256, 0, stream>>>(x, rpb, w_qkv, b_qkv, w_proj, w_fc1, w_fc2,
                                   xsb, wqkvp, bqkvp, wprojb, wfc1b, wfc2b, bm);
  k_attn<<<4096, 256, 0, stream>>>(xsb, wqkvp, bqkvp, wprojb, b_proj,
                                   g0, be0, g1, be1, bm, xs2b);
  k_mlp_fused<<<1568, 512, 0, stream>>>(xsb, wfc1b, b_fc1, wfc2b, b_fc2, xs2b, out);
}